// Round 3
// baseline (1908.432 us; speedup 1.0000x reference)
//
#include <hip/hip_runtime.h>
#include <math.h>

// Problem constants
#define B_    8
#define T_    12
#define BT    96          // B*T
#define NN    500
#define DD    512
#define KK    1024        // 2*D
#define SK    35          // SAMPLE_K == n_top
#define MROWS 48000       // BT*NN

typedef __bf16 bf16x8 __attribute__((ext_vector_type(8)));
typedef float f32x4 __attribute__((ext_vector_type(4)));
typedef unsigned short u16;
typedef u16 ushort8_t __attribute__((ext_vector_type(8)));
typedef u16 ushort4_t __attribute__((ext_vector_type(4)));

__device__ __forceinline__ u16 bf_hi(float x) {
  __bf16 h = (__bf16)x;
  return __builtin_bit_cast(u16, h);
}
__device__ __forceinline__ float bf_tof(u16 b) {
  unsigned int u = ((unsigned int)b) << 16;
  return __builtin_bit_cast(float, u);
}

// ---------------------------------------------------------------------------
// W -> W^T split into bf16 hi/lo:  Bt[n][k] = W[k][n]
// ---------------------------------------------------------------------------
__global__ __launch_bounds__(256) void convW_kernel(
    const float* __restrict__ W, u16* __restrict__ Bth, u16* __restrict__ Btl)
{
  const int n = blockIdx.x;          // 0..511
  const int k0 = threadIdx.x * 4;    // 0..1020
  float xs[4];
#pragma unroll
  for (int j = 0; j < 4; ++j) xs[j] = W[(size_t)(k0 + j) * 512 + n];
  ushort4_t hi, lo;
#pragma unroll
  for (int j = 0; j < 4; ++j) {
    u16 h = bf_hi(xs[j]);
    hi[j] = h;
    lo[j] = bf_hi(xs[j] - bf_tof(h));
  }
  *(ushort4_t*)(Bth + (size_t)n * 1024 + k0) = hi;
  *(ushort4_t*)(Btl + (size_t)n * 1024 + k0) = lo;
}

// ---------------------------------------------------------------------------
// MFMA projection GEMM: out = relu([X|STE] @ W + bias), C = [48000][512] f32.
// PASSES==3: split-bf16 (AhBh + AhBl + AlBh)  -> q, k.  PASSES==1: bf16 -> v.
// 1-D grid 1500: col-block-inner decode + bijective XCD swizzle (A-tile L2
// reuse across the 4 col-blocks of a row-block).
// ---------------------------------------------------------------------------
template<int PASSES>
__global__ __launch_bounds__(256) void mfma_proj(
    const float* __restrict__ X, const float* __restrict__ STE,
    const u16* __restrict__ Bth, const u16* __restrict__ Btl,
    const float* __restrict__ bias, float* __restrict__ out)
{
  __shared__ u16 lAh[128 * 32];
  __shared__ u16 lAl[128 * 32];
  __shared__ u16 lBh[128 * 32];
  __shared__ u16 lBl[128 * 32];
  const int tid = threadIdx.x;
  const int lane = tid & 63;
  const int wid = tid >> 6;
  const int wm = wid >> 1, wn = wid & 1;
  // bijective XCD swizzle over nwg=1500 (q=187, r=4)
  const int orig = blockIdx.x;
  const int xcd = orig & 7, pos = orig >> 3;
  const int wg = (xcd < 4 ? xcd * 188 : 752 + (xcd - 4) * 187) + pos;
  const int r0 = (wg >> 2) * 128;
  const int c0 = (wg & 3) * 128;
  const int fr = lane & 15, fk = lane >> 4;

  f32x4 acc[4][4];
#pragma unroll
  for (int m = 0; m < 4; ++m)
#pragma unroll
    for (int n = 0; n < 4; ++n) acc[m][n] = f32x4{0.f, 0.f, 0.f, 0.f};

  for (int kt = 0; kt < 32; ++kt) {
    const int kk0 = kt * 32;
#pragma unroll
    for (int p = 0; p < 2; ++p) {
      const int c = tid + p * 256;          // 0..511 chunk id
      const int row = c >> 2, kc = c & 3;
      const int dst = row * 32 + ((kc ^ (row & 3)) * 8);
      const int col = kk0 + kc * 8;
      const float* src = (col < 512)
          ? (X + (size_t)(r0 + row) * 512 + col)
          : (STE + (size_t)(r0 + row) * 512 + (col - 512));
      float4 x0 = *(const float4*)src;
      float4 x1 = *(const float4*)(src + 4);
      float xs[8] = {x0.x, x0.y, x0.z, x0.w, x1.x, x1.y, x1.z, x1.w};
      ushort8_t hi, lo;
#pragma unroll
      for (int j = 0; j < 8; ++j) {
        u16 h = bf_hi(xs[j]);
        hi[j] = h;
        if (PASSES == 3) lo[j] = bf_hi(xs[j] - bf_tof(h));
      }
      *(ushort8_t*)&lAh[dst] = hi;
      if (PASSES == 3) *(ushort8_t*)&lAl[dst] = lo;
      const size_t gb = (size_t)(c0 + row) * 1024 + kk0 + kc * 8;
      *(ushort8_t*)&lBh[dst] = *(const ushort8_t*)(Bth + gb);
      if (PASSES == 3) *(ushort8_t*)&lBl[dst] = *(const ushort8_t*)(Btl + gb);
    }
    __syncthreads();
    bf16x8 ah[4], al[4], bh[4], bl[4];
#pragma unroll
    for (int m = 0; m < 4; ++m) {
      const int row = wm * 64 + m * 16 + fr;
      const int off = row * 32 + ((fk ^ (row & 3)) * 8);
      ah[m] = *(const bf16x8*)&lAh[off];
      if (PASSES == 3) al[m] = *(const bf16x8*)&lAl[off];
    }
#pragma unroll
    for (int n = 0; n < 4; ++n) {
      const int row = wn * 64 + n * 16 + fr;
      const int off = row * 32 + ((fk ^ (row & 3)) * 8);
      bh[n] = *(const bf16x8*)&lBh[off];
      if (PASSES == 3) bl[n] = *(const bf16x8*)&lBl[off];
    }
#pragma unroll
    for (int m = 0; m < 4; ++m)
#pragma unroll
      for (int n = 0; n < 4; ++n) {
        acc[m][n] = __builtin_amdgcn_mfma_f32_16x16x32_bf16(
            ah[m], bh[n], acc[m][n], 0, 0, 0);
        if (PASSES == 3) {
          acc[m][n] = __builtin_amdgcn_mfma_f32_16x16x32_bf16(
              ah[m], bl[n], acc[m][n], 0, 0, 0);
          acc[m][n] = __builtin_amdgcn_mfma_f32_16x16x32_bf16(
              al[m], bh[n], acc[m][n], 0, 0, 0);
        }
      }
    __syncthreads();
  }
#pragma unroll
  for (int n = 0; n < 4; ++n) {
    const int col = c0 + wn * 64 + n * 16 + fr;
    const float bb = bias[col];
#pragma unroll
    for (int m = 0; m < 4; ++m) {
      const int rowb = r0 + wm * 64 + m * 16 + fk * 4;
#pragma unroll
      for (int r = 0; r < 4; ++r)
        out[(size_t)(rowb + r) * 512 + col] = fmaxf(acc[m][n][r] + bb, 0.f);
    }
  }
}

// ---------------------------------------------------------------------------
// K2: M[n] = max_s(q[n]·k[sidx]) - sum_s(...)/NN.  One wave per row.
// ---------------------------------------------------------------------------
__global__ __launch_bounds__(256) void sampled_M_kernel(
    const float* __restrict__ q, const float* __restrict__ k,
    const int* __restrict__ sidx, float* __restrict__ Mout)
{
  const int tid = threadIdx.x;
  const int lane = tid & 63, wid = tid >> 6;
  const int n = blockIdx.x * 4 + wid;       // 0..47999
  const int bt = n / NN, nn = n - bt * NN;
  const float* qrow = q + (size_t)n * DD + lane * 8;
  float4 q0 = *(const float4*)qrow;
  float4 q1 = *(const float4*)(qrow + 4);
  const float* kbase = k + (size_t)bt * NN * DD;
  float mx = -INFINITY, sm = 0.f;
  for (int s = 0; s < SK; ++s) {
    int m = sidx[nn * SK + s];
    const float* krow = kbase + (size_t)m * DD + lane * 8;
    float4 k0 = *(const float4*)krow;
    float4 k1 = *(const float4*)(krow + 4);
    float ss = q0.x*k0.x + q0.y*k0.y + q0.z*k0.z + q0.w*k0.w
             + q1.x*k1.x + q1.y*k1.y + q1.z*k1.z + q1.w*k1.w;
#pragma unroll
    for (int off = 32; off > 0; off >>= 1) ss += __shfl_xor(ss, off);
    mx = fmaxf(mx, ss);
    sm += ss;
  }
  if (lane == 0) Mout[n] = mx - sm * (1.0f / (float)NN);
}

// ---------------------------------------------------------------------------
// K3: top-35 (stable ties -> smaller index)
// ---------------------------------------------------------------------------
__global__ __launch_bounds__(256) void topk_kernel(
    const float* __restrict__ Mb, int* __restrict__ idxb)
{
  const int bt = blockIdx.x;
  const int tid = threadIdx.x;
  __shared__ float mv[NN];
  __shared__ float rv[256];
  __shared__ int ri[256];
  for (int n = tid; n < NN; n += 256) mv[n] = Mb[(size_t)bt * NN + n];
  __syncthreads();
  for (int it = 0; it < SK; ++it) {
    float bv = -INFINITY; int bi = NN;
    for (int n = tid; n < NN; n += 256) {
      float x = mv[n];
      if (x > bv) { bv = x; bi = n; }
    }
    rv[tid] = bv; ri[tid] = bi;
    __syncthreads();
    for (int sft = 128; sft > 0; sft >>= 1) {
      if (tid < sft) {
        float xv = rv[tid + sft]; int xi = ri[tid + sft];
        if (xv > rv[tid] || (xv == rv[tid] && xi < ri[tid])) {
          rv[tid] = xv; ri[tid] = xi;
        }
      }
      __syncthreads();
    }
    if (tid == 0) { idxb[bt * SK + it] = ri[0]; mv[ri[0]] = -INFINITY; }
    __syncthreads();
  }
}

// ---------------------------------------------------------------------------
// K4: per-(bt, u-half) attention. Phase1: scores for ~18 selected queries
// (k rows read once per block). Phase2: softmax in LDS. Phase3: PV with
// qi-sorted u-groups (per-group causal loop bound).
// ---------------------------------------------------------------------------
__global__ __launch_bounds__(512) void attn_bt_kernel(
    const float* __restrict__ q, const float* __restrict__ k,
    const float* __restrict__ v, const int* __restrict__ idxb,
    float* __restrict__ ctxn)
{
  const int half = blockIdx.x;       // 0/1
  const int bt = blockIdx.y;
  const int u0 = half * 18;
  const int ucnt = half ? (SK - 18) : 18;   // 18 / 17
  const int tid = threadIdx.x;
  const int lane = tid & 63, wid = tid >> 6;

  __shared__ float sc[18][512];
  __shared__ int qis[18];
  __shared__ int sorder[18];
  __shared__ float linv[18];

  float* scf = &sc[0][0];
  for (int i = tid; i < 18 * 512; i += 512) scf[i] = 0.f;
  if (tid < ucnt) qis[tid] = idxb[bt * SK + u0 + tid];
  __syncthreads();
  if (tid < ucnt) {               // rank by qi (indices distinct)
    int qi = qis[tid];
    int rank = 0;
    for (int j = 0; j < 18; ++j)
      if (j < ucnt) rank += (qis[j] < qi);
    sorder[rank] = tid;
  }
  __syncthreads();

  // ---- phase 1: scores ----
  const float scale = 0.044194173824159216f;   // 1/sqrt(512)
  for (int u = wid; u < ucnt; u += 8) {
    const int qi = qis[u];
    const float* qrow = q + ((size_t)bt * NN + qi) * DD + lane * 8;
    float4 q0 = *(const float4*)qrow;
    float4 q1 = *(const float4*)(qrow + 4);
    for (int m = 0; m <= qi; ++m) {
      const float* krow = k + ((size_t)bt * NN + m) * DD + lane * 8;
      float4 k0 = *(const float4*)krow;
      float4 k1 = *(const float4*)(krow + 4);
      float s = q0.x*k0.x + q0.y*k0.y + q0.z*k0.z + q0.w*k0.w
              + q1.x*k1.x + q1.y*k1.y + q1.z*k1.z + q1.w*k1.w;
#pragma unroll
      for (int off = 32; off > 0; off >>= 1) s += __shfl_xor(s, off);
      if (lane == 0) sc[u][m] = s * scale;
    }
  }
  __syncthreads();

  // ---- phase 2: softmax (store unnormalized exp + 1/sum) ----
  for (int u = wid; u < ucnt; u += 8) {
    const int qi = qis[u];
    float mx = -INFINITY;
    for (int m = lane; m <= qi; m += 64) mx = fmaxf(mx, sc[u][m]);
#pragma unroll
    for (int off = 32; off > 0; off >>= 1) mx = fmaxf(mx, __shfl_xor(mx, off));
    float sm = 0.f;
    for (int m = lane; m <= qi; m += 64) {
      float e = __expf(sc[u][m] - mx);
      sc[u][m] = e;
      sm += e;
    }
#pragma unroll
    for (int off = 32; off > 0; off >>= 1) sm += __shfl_xor(sm, off);
    if (lane == 0) linv[u] = 1.f / sm;
  }
  __syncthreads();

  // ---- phase 3: PV ----
  const int g = tid >> 7;            // u-group 0..3 (128 threads each)
  const int dq = tid & 127;          // float4 column
  const int npg = (ucnt + 3) >> 2;   // 5
  const int s0 = g * npg;
  const int s1 = (s0 + npg < ucnt) ? (s0 + npg) : ucnt;
  const int cnt = s1 - s0;
  float4 acc[5];
  int ulist[5], qlist[5];
#pragma unroll
  for (int i = 0; i < 5; ++i) {
    acc[i] = float4{0.f, 0.f, 0.f, 0.f};
    ulist[i] = 0; qlist[i] = -1;
    if (i < cnt) {
      int u = sorder[s0 + i];
      ulist[i] = u;
      qlist[i] = qis[u];
    }
  }
  int gmax = -1;
#pragma unroll
  for (int i = 0; i < 5; ++i) gmax = (qlist[i] > gmax) ? qlist[i] : gmax;
  const float4* v4 = (const float4*)(v + (size_t)bt * NN * DD);
  for (int m = 0; m <= gmax; ++m) {
    float4 vv = v4[(size_t)m * 128 + dq];
#pragma unroll
    for (int i = 0; i < 5; ++i) {
      if (m <= qlist[i]) {
        float w = sc[ulist[i]][m];
        acc[i].x = fmaf(w, vv.x, acc[i].x);
        acc[i].y = fmaf(w, vv.y, acc[i].y);
        acc[i].z = fmaf(w, vv.z, acc[i].z);
        acc[i].w = fmaf(w, vv.w, acc[i].w);
      }
    }
  }
#pragma unroll
  for (int i = 0; i < 5; ++i) {
    if (i < cnt) {
      int u = ulist[i];
      float inv = linv[u];
      float4 o;
      o.x = acc[i].x * inv; o.y = acc[i].y * inv;
      o.z = acc[i].z * inv; o.w = acc[i].w * inv;
      *(float4*)(ctxn + ((size_t)bt * SK + u0 + u) * DD + dq * 4) = o;
    }
  }
}

// ---------------------------------------------------------------------------
// K5: causal cumsum + scatter + transposed store. grid(2, 96), 256 thr.
// ---------------------------------------------------------------------------
__global__ __launch_bounds__(256) void cumsum_scatter_kernel(
    const float* __restrict__ v, const int* __restrict__ idxb,
    const float* __restrict__ ctxn, float* __restrict__ out)
{
  const int dh = blockIdx.x;
  const int bt = blockIdx.y;
  const int b = bt / T_, t = bt % T_;
  const int d = dh * 256 + threadIdx.x;
  __shared__ int sel[NN];
  for (int n = threadIdx.x; n < NN; n += 256) sel[n] = -1;
  __syncthreads();
  if (threadIdx.x < SK) sel[idxb[bt * SK + threadIdx.x]] = threadIdx.x;
  __syncthreads();
  float s = 0.f;
  for (int n = 0; n < NN; ++n) {
    s += v[((size_t)bt * NN + n) * DD + d];
    float o = s;
    int u = sel[n];
    if (u >= 0) o = ctxn[((size_t)bt * SK + u) * DD + d];
    out[(((size_t)b * NN + n) * T_ + t) * DD + d] = o;
  }
}

// ---------------------------------------------------------------------------
extern "C" void kernel_launch(void* const* d_in, const int* in_sizes, int n_in,
                              void* d_out, int out_size, void* d_ws, size_t ws_size,
                              hipStream_t stream) {
  const float* X   = (const float*)d_in[0];
  const float* STE = (const float*)d_in[1];
  const float* Wq  = (const float*)d_in[2];
  const float* bq  = (const float*)d_in[3];
  const float* Wk  = (const float*)d_in[4];
  const float* bk  = (const float*)d_in[5];
  const float* Wv  = (const float*)d_in[6];
  const float* bv  = (const float*)d_in[7];
  const int* sidx  = (const int*)d_in[8];
  float* out = (float*)d_out;

  float* q    = (float*)d_ws;
  float* k    = q + (size_t)MROWS * DD;
  float* v    = k + (size_t)MROWS * DD;
  float* Mb   = v + (size_t)MROWS * DD;          // 48,000 f32
  int*   idxb = (int*)(Mb + MROWS);              // 3,360 i32
  float* ctxn = (float*)(idxb + BT * SK);        // 1,720,320 f32
  u16* Bqh = (u16*)(ctxn + (size_t)BT * SK * DD);
  u16* Bql = Bqh + (size_t)512 * 1024;
  u16* Bkh = Bql + (size_t)512 * 1024;
  u16* Bkl = Bkh + (size_t)512 * 1024;
  u16* Bvh = Bkl + (size_t)512 * 1024;
  u16* Bvl = Bvh + (size_t)512 * 1024;
  (void)ws_size; (void)in_sizes; (void)n_in; (void)out_size;

  convW_kernel<<<512, 256, 0, stream>>>(Wq, Bqh, Bql);
  convW_kernel<<<512, 256, 0, stream>>>(Wk, Bkh, Bkl);
  convW_kernel<<<512, 256, 0, stream>>>(Wv, Bvh, Bvl);

  mfma_proj<3><<<1500, 256, 0, stream>>>(X, STE, Bqh, Bql, bq, q);
  mfma_proj<3><<<1500, 256, 0, stream>>>(X, STE, Bkh, Bkl, bk, k);
  mfma_proj<1><<<1500, 256, 0, stream>>>(X, STE, Bvh, Bvl, bv, v);

  sampled_M_kernel<<<MROWS / 4, 256, 0, stream>>>(q, k, sidx, Mb);
  topk_kernel<<<BT, 256, 0, stream>>>(Mb, idxb);
  dim3 ga(2, BT);
  attn_bt_kernel<<<ga, 512, 0, stream>>>(q, k, v, idxb, ctxn);
  dim3 gc(2, BT);
  cumsum_scatter_kernel<<<gc, 256, 0, stream>>>(v, idxb, ctxn, out);
}

// Round 5
// 1058.573 us; speedup vs baseline: 1.8028x; 1.8028x over previous
//
#include <hip/hip_runtime.h>
#include <math.h>

// Problem constants
#define B_    8
#define T_    12
#define BT    96          // B*T
#define NN    500
#define DD    512
#define KK    1024        // 2*D
#define SK    35          // SAMPLE_K == n_top
#define MROWS 48000       // BT*NN

typedef __bf16 bf16x8 __attribute__((ext_vector_type(8)));
typedef float f32x4 __attribute__((ext_vector_type(4)));
typedef unsigned short u16;
typedef u16 ushort8_t __attribute__((ext_vector_type(8)));
typedef u16 ushort4_t __attribute__((ext_vector_type(4)));

__device__ __forceinline__ u16 bf_hi(float x) {
  __bf16 h = (__bf16)x;
  return __builtin_bit_cast(u16, h);
}
__device__ __forceinline__ float bf_tof(u16 b) {
  unsigned int u = ((unsigned int)b) << 16;
  return __builtin_bit_cast(float, u);
}

// ---------------------------------------------------------------------------
// W -> W^T split into bf16 hi/lo:  Bt[n][k] = W[k][n]
// ---------------------------------------------------------------------------
__global__ __launch_bounds__(256) void convW_kernel(
    const float* __restrict__ W, u16* __restrict__ Bth, u16* __restrict__ Btl)
{
  const int n = blockIdx.x;          // 0..511
  const int k0 = threadIdx.x * 4;    // 0..1020
  float xs[4];
#pragma unroll
  for (int j = 0; j < 4; ++j) xs[j] = W[(size_t)(k0 + j) * 512 + n];
  ushort4_t hi, lo;
#pragma unroll
  for (int j = 0; j < 4; ++j) {
    u16 h = bf_hi(xs[j]);
    hi[j] = h;
    lo[j] = bf_hi(xs[j] - bf_tof(h));
  }
  *(ushort4_t*)(Bth + (size_t)n * 1024 + k0) = hi;
  *(ushort4_t*)(Btl + (size_t)n * 1024 + k0) = lo;
}

// ---------------------------------------------------------------------------
// MFMA projection GEMM: out = relu([X|STE] @ W + bias).  A converted to
// bf16 hi/lo in the staging loop (r2-proven path, ws-footprint neutral).
// PASSES==3: AhBh + AhBl + AlBh -> q, k.   PASSES==1: AhBh -> v.
// BM=BN=128, BK=32, 256 thr (4 waves 2x2), 16x16x32 MFMA, 4x4 frags/wave.
// 1-D grid 1500, col-inner decode + bijective XCD swizzle.
// ---------------------------------------------------------------------------
template<int PASSES>
__global__ __launch_bounds__(256) void mfma_proj(
    const float* __restrict__ X, const float* __restrict__ STE,
    const u16* __restrict__ Bth, const u16* __restrict__ Btl,
    const float* __restrict__ bias, float* __restrict__ out)
{
  constexpr int NT = (PASSES == 3) ? 4 : 2;
  __shared__ u16 ldsbuf[NT * 4096];
  u16* lAh = ldsbuf;
  u16* lBh = ldsbuf + 4096;
  u16* lAl = ldsbuf + ((NT == 4) ? 8192 : 0);
  u16* lBl = ldsbuf + ((NT == 4) ? 12288 : 0);
  const int tid = threadIdx.x;
  const int lane = tid & 63;
  const int wid = tid >> 6;
  const int wm = wid >> 1, wn = wid & 1;
  // bijective XCD swizzle over nwg=1500 (q=187, r=4)
  const int orig = blockIdx.x;
  const int xcd = orig & 7, pos = orig >> 3;
  const int wg = (xcd < 4 ? xcd * 188 : 752 + (xcd - 4) * 187) + pos;
  const int r0 = (wg >> 2) * 128;
  const int c0 = (wg & 3) * 128;
  const int fr = lane & 15, fk = lane >> 4;

  f32x4 acc[4][4];
#pragma unroll
  for (int m = 0; m < 4; ++m)
#pragma unroll
    for (int n = 0; n < 4; ++n) acc[m][n] = f32x4{0.f, 0.f, 0.f, 0.f};

  for (int kt = 0; kt < 32; ++kt) {
    const int kk0 = kt * 32;
#pragma unroll
    for (int p = 0; p < 2; ++p) {
      const int c = tid + p * 256;          // 0..511 chunk id
      const int row = c >> 2, kc = c & 3;
      const int dst = row * 32 + ((kc ^ (row & 3)) * 8);
      const int col = kk0 + kc * 8;
      const float* src = (col < 512)
          ? (X + (size_t)(r0 + row) * 512 + col)
          : (STE + (size_t)(r0 + row) * 512 + (col - 512));
      float4 x0 = *(const float4*)src;
      float4 x1 = *(const float4*)(src + 4);
      float xs[8] = {x0.x, x0.y, x0.z, x0.w, x1.x, x1.y, x1.z, x1.w};
      ushort8_t hi, lo;
#pragma unroll
      for (int j = 0; j < 8; ++j) {
        u16 h = bf_hi(xs[j]);
        hi[j] = h;
        if (PASSES == 3) lo[j] = bf_hi(xs[j] - bf_tof(h));
      }
      *(ushort8_t*)&lAh[dst] = hi;
      if (PASSES == 3) *(ushort8_t*)&lAl[dst] = lo;
      const size_t gb = (size_t)(c0 + row) * 1024 + kk0 + kc * 8;
      *(ushort8_t*)&lBh[dst] = *(const ushort8_t*)(Bth + gb);
      if (PASSES == 3) *(ushort8_t*)&lBl[dst] = *(const ushort8_t*)(Btl + gb);
    }
    __syncthreads();
    bf16x8 ah[4], al[4], bh[4], bl[4];
#pragma unroll
    for (int m = 0; m < 4; ++m) {
      const int row = wm * 64 + m * 16 + fr;
      const int off = row * 32 + ((fk ^ (row & 3)) * 8);
      ah[m] = *(const bf16x8*)&lAh[off];
      if (PASSES == 3) al[m] = *(const bf16x8*)&lAl[off];
    }
#pragma unroll
    for (int n = 0; n < 4; ++n) {
      const int row = wn * 64 + n * 16 + fr;
      const int off = row * 32 + ((fk ^ (row & 3)) * 8);
      bh[n] = *(const bf16x8*)&lBh[off];
      if (PASSES == 3) bl[n] = *(const bf16x8*)&lBl[off];
    }
#pragma unroll
    for (int m = 0; m < 4; ++m)
#pragma unroll
      for (int n = 0; n < 4; ++n) {
        acc[m][n] = __builtin_amdgcn_mfma_f32_16x16x32_bf16(
            ah[m], bh[n], acc[m][n], 0, 0, 0);
        if (PASSES == 3) {
          acc[m][n] = __builtin_amdgcn_mfma_f32_16x16x32_bf16(
              ah[m], bl[n], acc[m][n], 0, 0, 0);
          acc[m][n] = __builtin_amdgcn_mfma_f32_16x16x32_bf16(
              al[m], bh[n], acc[m][n], 0, 0, 0);
        }
      }
    __syncthreads();
  }
#pragma unroll
  for (int n = 0; n < 4; ++n) {
    const int col = c0 + wn * 64 + n * 16 + fr;
    const float bb = bias[col];
#pragma unroll
    for (int m = 0; m < 4; ++m) {
      const int rowb = r0 + wm * 64 + m * 16 + fk * 4;
#pragma unroll
      for (int r = 0; r < 4; ++r)
        out[(size_t)(rowb + r) * 512 + col] = fmaxf(acc[m][n][r] + bb, 0.f);
    }
  }
}

// ---------------------------------------------------------------------------
// K2: M[n] = max_s(q[n]·k[sidx]) - sum_s(...)/NN.  One wave per row.
// XCD-pinned: all rows of one bt land on one XCD (k[bt] stays in its L2).
// ---------------------------------------------------------------------------
__global__ __launch_bounds__(256) void sampled_M_kernel(
    const float* __restrict__ q, const float* __restrict__ k,
    const int* __restrict__ sidx, float* __restrict__ Mout)
{
  const int tid = threadIdx.x;
  const int lane = tid & 63, wid = tid >> 6;
  const int bid = blockIdx.x;               // 0..11999
  const int xcd = bid & 7, j = bid >> 3;    // j 0..1499
  const int btg = j / 125, ub = j - btg * 125;
  const int bt = btg * 8 + xcd;
  const int nn = ub * 4 + wid;              // 0..499
  const int n = bt * NN + nn;
  const float* qrow = q + (size_t)n * DD + lane * 8;
  float4 q0 = *(const float4*)qrow;
  float4 q1 = *(const float4*)(qrow + 4);
  const float* kbase = k + (size_t)bt * NN * DD;
  float mx = -INFINITY, sm = 0.f;
  for (int s = 0; s < SK; ++s) {
    int m = sidx[nn * SK + s];
    const float* krow = kbase + (size_t)m * DD + lane * 8;
    float4 k0 = *(const float4*)krow;
    float4 k1 = *(const float4*)(krow + 4);
    float ss = q0.x*k0.x + q0.y*k0.y + q0.z*k0.z + q0.w*k0.w
             + q1.x*k1.x + q1.y*k1.y + q1.z*k1.z + q1.w*k1.w;
#pragma unroll
    for (int off = 32; off > 0; off >>= 1) ss += __shfl_xor(ss, off);
    mx = fmaxf(mx, ss);
    sm += ss;
  }
  if (lane == 0) Mout[n] = mx - sm * (1.0f / (float)NN);
}

// ---------------------------------------------------------------------------
// K3: top-35 (stable ties -> smaller index)
// ---------------------------------------------------------------------------
__global__ __launch_bounds__(256) void topk_kernel(
    const float* __restrict__ Mb, int* __restrict__ idxb)
{
  const int bt = blockIdx.x;
  const int tid = threadIdx.x;
  __shared__ float mv[NN];
  __shared__ float rv[256];
  __shared__ int ri[256];
  for (int n = tid; n < NN; n += 256) mv[n] = Mb[(size_t)bt * NN + n];
  __syncthreads();
  for (int it = 0; it < SK; ++it) {
    float bv = -INFINITY; int bi = NN;
    for (int n = tid; n < NN; n += 256) {
      float x = mv[n];
      if (x > bv) { bv = x; bi = n; }
    }
    rv[tid] = bv; ri[tid] = bi;
    __syncthreads();
    for (int sft = 128; sft > 0; sft >>= 1) {
      if (tid < sft) {
        float xv = rv[tid + sft]; int xi = ri[tid + sft];
        if (xv > rv[tid] || (xv == rv[tid] && xi < ri[tid])) {
          rv[tid] = xv; ri[tid] = xi;
        }
      }
      __syncthreads();
    }
    if (tid == 0) { idxb[bt * SK + it] = ri[0]; mv[ri[0]] = -INFINITY; }
    __syncthreads();
  }
}

// ---------------------------------------------------------------------------
// K4: causal softmax + PV, one block per (bt,u). XCD-pinned: the 35 blocks
// of one bt share the XCD L2 (k+v = 2 MB <= 4 MB).
// ---------------------------------------------------------------------------
__global__ __launch_bounds__(256) void attn_sel_kernel(
    const float* __restrict__ q, const float* __restrict__ k,
    const float* __restrict__ v, const int* __restrict__ idxb,
    float* __restrict__ ctxn)
{
  const int bid = blockIdx.x;               // 0..3359
  const int xcd = bid & 7, j = bid >> 3;    // j 0..419
  const int btg = j / 35, u = j - btg * 35;
  const int bt = btg * 8 + xcd;
  const int tid = threadIdx.x;
  const int lane = tid & 63, wid = tid >> 6;
  const int qi = idxb[bt * SK + u];
  __shared__ float qs[DD];
  __shared__ float sc[NN];
  __shared__ float wred[4];
  for (int c = tid; c < DD; c += 256)
    qs[c] = q[((size_t)bt * NN + qi) * DD + c];
  __syncthreads();
  const float scale = 0.044194173824159216f;   // 1/sqrt(512)
  for (int m = wid; m <= qi; m += 4) {
    const float* krow = k + ((size_t)bt * NN + m) * DD;
    float sum = 0.f;
#pragma unroll
    for (int c = lane; c < DD; c += 64) sum += qs[c] * krow[c];
#pragma unroll
    for (int off = 32; off > 0; off >>= 1) sum += __shfl_down(sum, off);
    if (lane == 0) sc[m] = sum * scale;
  }
  __syncthreads();
  float lm = -INFINITY;
  for (int m = tid; m <= qi; m += 256) lm = fmaxf(lm, sc[m]);
#pragma unroll
  for (int off = 32; off > 0; off >>= 1) lm = fmaxf(lm, __shfl_down(lm, off));
  if (lane == 0) wred[wid] = lm;
  __syncthreads();
  float mx = fmaxf(fmaxf(wred[0], wred[1]), fmaxf(wred[2], wred[3]));
  __syncthreads();
  float ls = 0.f;
  for (int m = tid; m <= qi; m += 256) {
    float e = expf(sc[m] - mx);
    sc[m] = e;
    ls += e;
  }
#pragma unroll
  for (int off = 32; off > 0; off >>= 1) ls += __shfl_down(ls, off);
  if (lane == 0) wred[wid] = ls;
  __syncthreads();
  float inv = 1.f / (wred[0] + wred[1] + wred[2] + wred[3]);
  float acc0 = 0.f, acc1 = 0.f;
  for (int m = 0; m <= qi; ++m) {
    float w_ = sc[m];
    const float* vrow = v + ((size_t)bt * NN + m) * DD;
    acc0 = fmaf(w_, vrow[tid], acc0);
    acc1 = fmaf(w_, vrow[tid + 256], acc1);
  }
  const size_t ob = ((size_t)bt * SK + u) * DD;
  ctxn[ob + tid] = acc0 * inv;
  ctxn[ob + tid + 256] = acc1 * inv;
}

// ---------------------------------------------------------------------------
// K5: causal cumsum + scatter + transposed store. grid(2, 96), 256 thr.
// ---------------------------------------------------------------------------
__global__ __launch_bounds__(256) void cumsum_scatter_kernel(
    const float* __restrict__ v, const int* __restrict__ idxb,
    const float* __restrict__ ctxn, float* __restrict__ out)
{
  const int dh = blockIdx.x;
  const int bt = blockIdx.y;
  const int b = bt / T_, t = bt % T_;
  const int d = dh * 256 + threadIdx.x;
  __shared__ int sel[NN];
  for (int n = threadIdx.x; n < NN; n += 256) sel[n] = -1;
  __syncthreads();
  if (threadIdx.x < SK) sel[idxb[bt * SK + threadIdx.x]] = threadIdx.x;
  __syncthreads();
  float s = 0.f;
  for (int n = 0; n < NN; ++n) {
    s += v[((size_t)bt * NN + n) * DD + d];
    float o = s;
    int u = sel[n];
    if (u >= 0) o = ctxn[((size_t)bt * SK + u) * DD + d];
    out[(((size_t)b * NN + n) * T_ + t) * DD + d] = o;
  }
}

// ---------------------------------------------------------------------------
extern "C" void kernel_launch(void* const* d_in, const int* in_sizes, int n_in,
                              void* d_out, int out_size, void* d_ws, size_t ws_size,
                              hipStream_t stream) {
  const float* X   = (const float*)d_in[0];
  const float* STE = (const float*)d_in[1];
  const float* Wq  = (const float*)d_in[2];
  const float* bq  = (const float*)d_in[3];
  const float* Wk  = (const float*)d_in[4];
  const float* bk  = (const float*)d_in[5];
  const float* Wv  = (const float*)d_in[6];
  const float* bv  = (const float*)d_in[7];
  const int* sidx  = (const int*)d_in[8];
  float* out = (float*)d_out;

  // workspace: q | k | v | M | idx | ctx_new | B splits  (~308.4 MB, proven)
  float* q    = (float*)d_ws;
  float* k    = q + (size_t)MROWS * DD;
  float* v    = k + (size_t)MROWS * DD;
  float* Mb   = v + (size_t)MROWS * DD;          // 48,000 f32
  int*   idxb = (int*)(Mb + MROWS);              // 3,360 i32
  float* ctxn = (float*)(idxb + BT * SK);        // 1,720,320 f32
  u16* Bqh = (u16*)(ctxn + (size_t)BT * SK * DD);
  u16* Bql = Bqh + (size_t)512 * 1024;
  u16* Bkh = Bql + (size_t)512 * 1024;
  u16* Bkl = Bkh + (size_t)512 * 1024;
  u16* Bvh = Bkl + (size_t)512 * 1024;
  u16* Bvl = Bvh + (size_t)512 * 1024;
  (void)ws_size; (void)in_sizes; (void)n_in; (void)out_size;

  convW_kernel<<<512, 256, 0, stream>>>(Wq, Bqh, Bql);
  convW_kernel<<<512, 256, 0, stream>>>(Wk, Bkh, Bkl);
  convW_kernel<<<512, 256, 0, stream>>>(Wv, Bvh, Bvl);

  mfma_proj<3><<<1500, 256, 0, stream>>>(X, STE, Bqh, Bql, bq, q);
  mfma_proj<3><<<1500, 256, 0, stream>>>(X, STE, Bkh, Bkl, bk, k);
  mfma_proj<1><<<1500, 256, 0, stream>>>(X, STE, Bvh, Bvl, bv, v);

  sampled_M_kernel<<<12000, 256, 0, stream>>>(q, k, sidx, Mb);
  topk_kernel<<<BT, 256, 0, stream>>>(Mb, idxb);
  attn_sel_kernel<<<3360, 256, 0, stream>>>(q, k, v, idxb, ctxn);
  dim3 gc(2, BT);
  cumsum_scatter_kernel<<<gc, 256, 0, stream>>>(v, idxb, ctxn, out);
}